// Round 4
// baseline (738.065 us; speedup 1.0000x reference)
//
#include <hip/hip_runtime.h>
#include <math.h>

#define FH 160
#define FW 160
#define NPOS (FH*FW)        // 25600
#define NANCH (NPOS*9)      // 230400
#define IMG 2560.0f
#define STRIDE 16.0f

typedef __attribute__((ext_vector_type(8))) short short8;
typedef __attribute__((ext_vector_type(4))) float f32x4;

__device__ __forceinline__ unsigned short bf16_rne(float v) {
    unsigned u = __float_as_uint(v);
    return (unsigned short)((u + 0x7FFFu + ((u >> 16) & 1u)) >> 16);
}
__device__ __forceinline__ float bf16_to_f(unsigned short b) {
    return __uint_as_float(((unsigned)b) << 16);
}
__device__ __forceinline__ void g2l16(void* lds, const void* g) {
    __builtin_amdgcn_global_load_lds(
        (const __attribute__((address_space(1))) void*)g,
        (__attribute__((address_space(3))) void*)lds, 16, 0, 0);
}

// ---------------------------------------------------------------------------
// prep: fused fprep (pad+bf16 features) / wprep2 (conv1 W transpose+split)
// / whprep (head W pack+split). One launch instead of three.
// ---------------------------------------------------------------------------
__global__ __launch_bounds__(256) void prep_kernel(
    const float* __restrict__ f, const float* __restrict__ w,
    const float* __restrict__ regw, const float* __restrict__ clsw,
    const float* __restrict__ lmw,
    unsigned short* __restrict__ fph,
    unsigned short* __restrict__ wth, unsigned short* __restrict__ wtl,
    unsigned short* __restrict__ whh, unsigned short* __restrict__ whl)
{
    __shared__ float tile[32][33];
    const int bid = blockIdx.x, t = threadIdx.x;
    if (bid < 13122) {                      // ---- fprep: 162*162*128 threads
        int idx = bid*256 + t;
        int c4 = (idx & 127) << 2;
        int rest = idx >> 7;
        int x = rest % 162, y = rest / 162;
        float4 v = make_float4(0.f, 0.f, 0.f, 0.f);
        if (y > 0 && y < 161 && x > 0 && x < 161)
            v = *(const float4*)(f + ((size_t)((y-1)*FW + (x-1)) << 9) + c4);
        ushort4 h;
        h.x = bf16_rne(v.x); h.y = bf16_rne(v.y);
        h.z = bf16_rne(v.z); h.w = bf16_rne(v.w);
        *(ushort4*)(fph + ((size_t)(y*162 + x) << 9) + c4) = h;
    } else if (bid < 15426) {               // ---- wprep2: 144 x 16 tiles
        int b = bid - 13122;
        int k0 = (b % 144)*32, oc0 = (b / 144)*32;
        int c = t & 31, r8 = t >> 5;
#pragma unroll
        for (int i = 0; i < 4; ++i) {
            int r = r8 + i*8;
            tile[c][r] = w[(size_t)(k0 + r)*512 + oc0 + c];
        }
        __syncthreads();
#pragma unroll
        for (int i = 0; i < 4; ++i) {
            int orow = r8 + i*8, kcol = c;
            float v = tile[orow][kcol];
            unsigned short hi = bf16_rne(v);
            unsigned short lo = bf16_rne(v - bf16_to_f(hi));
            size_t o = (size_t)(oc0 + orow)*4608 + k0 + kcol;
            wth[o] = hi; wtl[o] = lo;
        }
    } else {                                // ---- whprep: 128x512 pack
        int i = (bid - 15426)*256 + t;
        int u = i >> 9, c = i & 511;
        float v = 0.f;
        if (u < 36)      v = regw[c*72 + (u>>2)*8 + (u&3)];
        else if (u < 45) v = clsw[c*9 + (u-36)];
        else if (u < 99) v = lmw[c*54 + (u-45)];
        unsigned short h = bf16_rne(v);
        whh[i] = h; whl[i] = bf16_rne(v - bf16_to_f(h));
    }
}

// ---------------------------------------------------------------------------
// conv1 MFMA, 2-term (Ah*Bh + Ah*Bl). Block = 128 thr (2 waves), tile
// BM=128 x BN=128, wave tile 128x64 (8 m-blocks x 4 n-blocks of 16x16x32).
// Rationale: LDS bytes/MAC ~ (M+2N)/(MN); 128x64 wave tile gives 1.5x the
// LDS-port efficiency of 64x64 — round-3 cycle model showed LDS-port-bound
// at 40%. Full 3-bit XOR swizzle (chunk ^= row&7) applied via global addr
// permutation (global_load_lds LDS addr is forced linear base+lane*16).
// ---------------------------------------------------------------------------
__global__ __launch_bounds__(128, 2) void conv1_mfma_kernel(
    const unsigned short* __restrict__ fph,
    const unsigned short* __restrict__ wth, const unsigned short* __restrict__ wtl,
    const float* __restrict__ bias, unsigned short* __restrict__ xh)
{
    __shared__ unsigned short As[128*64];
    __shared__ unsigned short Bh[128*64];
    __shared__ unsigned short Bl[128*64];
    const int tid  = threadIdx.x;
    const int lane = tid & 63;
    const int wv   = tid >> 6;               // wave id: n-half
    const int bid  = blockIdx.x;
    const int xcd  = bid & 7, sl = bid >> 3;
    const int oc0  = (xcd & 3) * 128;
    const int pt   = (xcd >> 2) * 100 + sl;
    const int ty = pt / 5, tx = pt - ty*5;
    const int y0 = ty*4, x0 = tx*32;

    const int srow0 = tid >> 3;              // 0..15
    const int kswz  = (((tid & 7) ^ (srow0 & 7)) << 3);
    const int quad = lane >> 4, fr = lane & 15;

    f32x4 acc[8][4] = {};

    // B staging global row for round p: oc0 + srow0 + p*16
    const size_t bBase = (size_t)(oc0 + srow0)*4608 + kswz;

    for (int tap = 0; tap < 9; ++tap) {
        const int ky = tap/3, kx = tap - (tap/3)*3;
        // A staging rows: row_p = srow0 + p*16 -> ry=p>>1, rx=(p&1)*16+srow0
        size_t aBase[8];
#pragma unroll
        for (int p = 0; p < 8; ++p)
            aBase[p] = ((size_t)((y0 + (p>>1) + ky)*162 + (x0 + (p&1)*16 + srow0 + kx)) << 9) + kswz;
        const size_t bTap = bBase + tap*512;
        for (int icb = 0; icb < 512; icb += 64) {
#pragma unroll
            for (int p = 0; p < 8; ++p) {
                g2l16(As + tid*8 + p*1024, fph + aBase[p] + icb);
                g2l16(Bh + tid*8 + p*1024, wth + bTap + (size_t)p*16*4608 + icb);
                g2l16(Bl + tid*8 + p*1024, wtl + bTap + (size_t)p*16*4608 + icb);
            }
            __syncthreads();
#pragma unroll
            for (int kk = 0; kk < 2; ++kk) {
                const int sa = ((kk*4 + quad) ^ (fr & 7)) << 3;
                short8 a[8], bh[4], bl[4];
#pragma unroll
                for (int mb = 0; mb < 8; ++mb)
                    a[mb] = *(const short8*)(As + (mb*16 + fr)*64 + sa);
#pragma unroll
                for (int nb = 0; nb < 4; ++nb) {
                    int off = (wv*64 + nb*16 + fr)*64 + sa;
                    bh[nb] = *(const short8*)(Bh + off);
                    bl[nb] = *(const short8*)(Bl + off);
                }
#pragma unroll
                for (int mb = 0; mb < 8; ++mb)
#pragma unroll
                    for (int nb = 0; nb < 4; ++nb) {
                        acc[mb][nb] = __builtin_amdgcn_mfma_f32_16x16x32_bf16(a[mb], bh[nb], acc[mb][nb], 0, 0, 0);
                        acc[mb][nb] = __builtin_amdgcn_mfma_f32_16x16x32_bf16(a[mb], bl[nb], acc[mb][nb], 0, 0, 0);
                    }
            }
            __syncthreads();
        }
    }

    // epilogue: C/D col=lane&15 (oc), row=(lane>>4)*4+reg (pos); ReLU -> bf16
#pragma unroll
    for (int mb = 0; mb < 8; ++mb) {
#pragma unroll
        for (int r = 0; r < 4; ++r) {
            int mi = mb*16 + quad*4 + r;
            int p = (y0 + (mi >> 5))*FW + x0 + (mi & 31);
#pragma unroll
            for (int nb = 0; nb < 4; ++nb) {
                int col = oc0 + wv*64 + nb*16 + fr;
                float v = acc[mb][nb][r] + bias[col];
                xh[(size_t)p*512 + col] = bf16_rne(v > 0.f ? v : 0.f);
            }
        }
    }
}

// ---------------------------------------------------------------------------
// heads via MFMA + FUSED decode/anchors. GEMM M=25600, N=128(99), K=512,
// 2-term. Epilogue stages deltas+cls into LDS, then decodes 128x9 anchors
// per block: writes boxes, anch_out, masked sigmoid scores. Also zeroes the
// NMS slot array (block 0).
// ---------------------------------------------------------------------------
__global__ __launch_bounds__(256) void heads_mfma_kernel(
    const unsigned short* __restrict__ xh,
    const unsigned short* __restrict__ whh, const unsigned short* __restrict__ whl,
    const float* __restrict__ regb, const float* __restrict__ clsb,
    const float* __restrict__ lmb,
    float* __restrict__ lm_out, float* __restrict__ boxes,
    float* __restrict__ anch_out, float* __restrict__ s_arr,
    unsigned long long* __restrict__ slot)
{
    __shared__ unsigned short As[128*64];
    __shared__ unsigned short Bh[128*64];
    __shared__ unsigned short Bl[128*64];
    __shared__ float sdel[128][40];   // 36 used, pad to 40
    __shared__ float scls[128][12];   // 9 used
    const int tid  = threadIdx.x;
    const int lane = tid & 63;
    const int wi   = (tid >> 7) & 1;
    const int wj   = (tid >> 6) & 1;
    const int p0   = blockIdx.x * 128;

    const int srow0 = tid >> 3;              // 0..31
    const int kswz  = (((tid & 7) ^ (srow0 & 7)) << 3);
    const int quad = lane >> 4, fr = lane & 15;
    f32x4 acc[4][4] = {};

    const size_t aOfs = ((size_t)(p0 + srow0) << 9) + kswz;
    const size_t bOfs = ((size_t)srow0 << 9) + kswz;

    for (int icb = 0; icb < 512; icb += 64) {
#pragma unroll
        for (int p = 0; p < 4; ++p) {
            g2l16(As + tid*8 + p*2048, xh  + aOfs + (size_t)p*32*512 + icb);
            g2l16(Bh + tid*8 + p*2048, whh + bOfs + (size_t)p*32*512 + icb);
            g2l16(Bl + tid*8 + p*2048, whl + bOfs + (size_t)p*32*512 + icb);
        }
        __syncthreads();
#pragma unroll
        for (int kk = 0; kk < 2; ++kk) {
            const int sa = ((kk*4 + quad) ^ (fr & 7)) << 3;
            short8 a[4], bhv[4], blv[4];
#pragma unroll
            for (int b = 0; b < 4; ++b) {
                a[b]   = *(const short8*)(As + (wi*64 + b*16 + fr)*64 + sa);
                bhv[b] = *(const short8*)(Bh + (wj*64 + b*16 + fr)*64 + sa);
                blv[b] = *(const short8*)(Bl + (wj*64 + b*16 + fr)*64 + sa);
            }
#pragma unroll
            for (int i = 0; i < 4; ++i)
#pragma unroll
                for (int j = 0; j < 4; ++j) {
                    acc[i][j] = __builtin_amdgcn_mfma_f32_16x16x32_bf16(a[i], bhv[j], acc[i][j], 0, 0, 0);
                    acc[i][j] = __builtin_amdgcn_mfma_f32_16x16x32_bf16(a[i], blv[j], acc[i][j], 0, 0, 0);
                }
        }
        __syncthreads();
    }

    // scatter results: deltas & cls to LDS, landmarks straight to global
#pragma unroll
    for (int i = 0; i < 4; ++i) {
#pragma unroll
        for (int r = 0; r < 4; ++r) {
            int pl = wi*64 + i*16 + quad*4 + r;
            int p = p0 + pl;
#pragma unroll
            for (int j = 0; j < 4; ++j) {
                int u = wj*64 + j*16 + fr;
                float v = acc[i][j][r];
                if (u < 36) {
                    sdel[pl][u] = v + regb[(u>>2)*8 + (u&3)];
                } else if (u < 45) {
                    float z = v + clsb[u-36];
                    scls[pl][u-36] = 1.f/(1.f + expf(-z));
                } else if (u < 99) {
                    lm_out[(size_t)p*54 + (u-45)] = v + lmb[u-45];
                }
            }
        }
    }
    if (blockIdx.x == 0 && tid < 8) slot[tid] = 0ull;
    __syncthreads();

    // fused decode: 128 positions x 9 anchors
    for (int t = tid; t < 128*9; t += 256) {
        int pl = t / 9, a = t - pl*9;
        int p = p0 + pl;
        int y = p / FW, x = p - FW*y;
        float cx = (x + 0.5f)*STRIDE, cy = (y + 0.5f)*STRIDE;
        const float rr[3] = {0.5f, 1.f, 2.f};
        const float ss[3] = {8.f, 16.f, 32.f};
        float r = rr[a/3], sv = ss[a - (a/3)*3];
        float h  = sqrtf(sv*sv/r)*STRIDE;
        float wvv = h * r;
        float x1a = cx - wvv*0.5f, y1a = cy - h*0.5f;
        float x2a = cx + wvv*0.5f, y2a = cy + h*0.5f;
        size_t n = (size_t)p*9 + a;
        float4 av = {x1a, y1a, x2a, y2a};
        *(float4*)(anch_out + 4*n) = av;
        bool valid = (x1a >= 0.f) && (y1a >= 0.f) && (x2a <= IMG) && (y2a <= IMG);

        float dx = sdel[pl][a*4+0], dy = sdel[pl][a*4+1];
        float dw = sdel[pl][a*4+2], dh = sdel[pl][a*4+3];
        float px = cx + wvv*dx, py = cy + h*dy;
        float pw = wvv*expf(dw), ph = h*expf(dh);
        float bx1 = px - pw*0.5f, by1 = py - ph*0.5f;
        float4 b;
        b.x = fminf(fmaxf(bx1, 0.f), IMG);
        b.y = fminf(fmaxf(by1, 0.f), IMG);
        b.z = fminf(fmaxf(bx1 + pw, 0.f), IMG);
        b.w = fminf(fmaxf(by1 + ph, 0.f), IMG);
        *(float4*)(boxes + 4*n) = b;
        s_arr[n] = valid ? scls[pl][a] : -1.f;
    }
}

// ---------------------------------------------------------------------------
// NMS round k: suppress vs winner from slot[k-1], argmax into slot[k].
// Packed (sortable score, ~index) u64 preserves jnp.argmax tie-break
// (max score, lowest index). 7 launches total instead of 12.
// ---------------------------------------------------------------------------
__global__ __launch_bounds__(256) void nms_iter_kernel(
    const float* __restrict__ boxes, float* __restrict__ s_arr,
    unsigned long long* __restrict__ slot, int k)
{
    int n = blockIdx.x*256 + threadIdx.x;
    float s = s_arr[n];
    if (k > 0) {
        unsigned int wn = ~(unsigned int)(slot[k-1] & 0xFFFFFFFFull);
        float4 wb = *(const float4*)(boxes + (size_t)4*wn);
        float4 b  = *(const float4*)(boxes + (size_t)4*n);
        float ix = fminf(wb.z, b.z) - fmaxf(wb.x, b.x);
        float iy = fminf(wb.w, b.w) - fmaxf(wb.y, b.y);
        float inter = fmaxf(ix, 0.f)*fmaxf(iy, 0.f);
        float a1 = (wb.z-wb.x)*(wb.w-wb.y);
        float a2 = (b.z-b.x)*(b.w-b.y);
        float iou = inter/(a1 + a2 - inter + 1e-9f);
        if (iou > 0.5f) { s = -1.f; s_arr[n] = -1.f; }
    }
    unsigned int bu = __float_as_uint(s);
    unsigned int key = (bu & 0x80000000u) ? ~bu : (bu | 0x80000000u);
    unsigned long long packed =
        ((unsigned long long)key << 32) | (unsigned int)~(unsigned int)n;
#pragma unroll
    for (int off = 32; off > 0; off >>= 1) {
        unsigned long long o = __shfl_xor(packed, off, 64);
        packed = packed > o ? packed : o;
    }
    if ((threadIdx.x & 63) == 0) atomicMax(&slot[k], packed);
}

__global__ void nms_fin_kernel(
    const float* __restrict__ boxes,
    const unsigned long long* __restrict__ slot, float* __restrict__ rois)
{
    int t = threadIdx.x;
    if (t < 6) {
        unsigned int n = ~(unsigned int)(slot[t] & 0xFFFFFFFFull);
        float4 b = *(const float4*)(boxes + (size_t)4*n);
        *(float4*)(rois + 4*t) = b;
    }
}

// ---------------------------------------------------------------------------
// fallback fp32 path kernels (known-good round-1 structure)
// ---------------------------------------------------------------------------
__global__ __launch_bounds__(256) void conv1_kernel(
    const float* __restrict__ f, const float* __restrict__ w,
    const float* __restrict__ bias, float* __restrict__ xout)
{
    __shared__ float As2[32][66];
    __shared__ float Bs2[32][66];
    const int tid = threadIdx.x;
    const int nt = blockIdx.x;
    const int mt = blockIdx.y;
    const int p0 = mt*64, oc0 = nt*64;
    const int tm = tid & 15, tn = tid >> 4;
    const int kA = tid & 31, mA = tid >> 5;
    const int nB = tid & 63, kB = tid >> 6;
    int yv[8], xv[8];
#pragma unroll
    for (int it = 0; it < 8; ++it) {
        int p = p0 + mA + it*8;
        yv[it] = p / FW;
        xv[it] = p - yv[it]*FW;
    }
    float acc[4][4] = {};
    for (int tap = 0; tap < 9; ++tap) {
        const int ky = tap/3 - 1, kx = tap%3 - 1;
        for (int icb = 0; icb < 512; icb += 32) {
#pragma unroll
            for (int it = 0; it < 8; ++it) {
                int yy = yv[it] + ky, xx = xv[it] + kx;
                float v = 0.f;
                if ((unsigned)yy < (unsigned)FH && (unsigned)xx < (unsigned)FW)
                    v = f[(((yy*FW)+xx)<<9) + icb + kA];
                As2[kA][mA + it*8] = v;
            }
            const float* wp = w + ((size_t)(tap*512 + icb + kB))*512 + oc0 + nB;
#pragma unroll
            for (int it = 0; it < 8; ++it)
                Bs2[kB + it*4][nB] = wp[(size_t)it*4*512];
            __syncthreads();
#pragma unroll 8
            for (int kk = 0; kk < 32; ++kk) {
                float a0 = As2[kk][4*tm+0], a1 = As2[kk][4*tm+1],
                      a2 = As2[kk][4*tm+2], a3 = As2[kk][4*tm+3];
                float b0 = Bs2[kk][4*tn+0], b1 = Bs2[kk][4*tn+1],
                      b2 = Bs2[kk][4*tn+2], b3 = Bs2[kk][4*tn+3];
                acc[0][0] += a0*b0; acc[0][1] += a0*b1; acc[0][2] += a0*b2; acc[0][3] += a0*b3;
                acc[1][0] += a1*b0; acc[1][1] += a1*b1; acc[1][2] += a1*b2; acc[1][3] += a1*b3;
                acc[2][0] += a2*b0; acc[2][1] += a2*b1; acc[2][2] += a2*b2; acc[2][3] += a2*b3;
                acc[3][0] += a3*b0; acc[3][1] += a3*b1; acc[3][2] += a3*b2; acc[3][3] += a3*b3;
            }
            __syncthreads();
        }
    }
#pragma unroll
    for (int i = 0; i < 4; ++i) {
        int p = p0 + 4*tm + i;
        float4 o;
        float* op = &o.x;
#pragma unroll
        for (int j = 0; j < 4; ++j) {
            float v = acc[i][j] + bias[oc0 + 4*tn + j];
            op[j] = v > 0.f ? v : 0.f;
        }
        *(float4*)(xout + (size_t)p*512 + oc0 + 4*tn) = o;
    }
}

__global__ __launch_bounds__(256) void wprep_kernel(
    const float* __restrict__ regw, const float* __restrict__ clsw,
    const float* __restrict__ lmw, float* __restrict__ wT)
{
    int i = blockIdx.x*256 + threadIdx.x;
    if (i >= 99*512) return;
    int u = i >> 9, c = i & 511;
    float v;
    if (u < 36)      v = regw[c*72 + (u>>2)*8 + (u&3)];
    else if (u < 45) v = clsw[c*9 + (u-36)];
    else             v = lmw[c*54 + (u-45)];
    wT[i] = v;
}

__global__ __launch_bounds__(256) void heads_kernel(
    const float* __restrict__ x, const float* __restrict__ wT,
    const float* __restrict__ regb, const float* __restrict__ clsb,
    const float* __restrict__ lmb,
    float* __restrict__ lm_out, float* __restrict__ deltas,
    float* __restrict__ s_arr)
{
    __shared__ float xs[16*516];
    const int p0 = blockIdx.x * 16;
    const float4* src = (const float4*)(x + (size_t)p0*512);
    for (int i = threadIdx.x; i < 16*128; i += 256) {
        int row = i >> 7, c4 = i & 127;
        *(float4*)(xs + row*516 + c4*4) = src[row*128 + c4];
    }
    __syncthreads();
    for (int oi = threadIdx.x; oi < 99*16; oi += 256) {
        int ps = oi & 15, u = oi >> 4;
        const float4* wv = (const float4*)(wT + (u << 9));
        const float4* xv = (const float4*)(xs + ps*516);
        float acc = 0.f;
#pragma unroll 4
        for (int c = 0; c < 128; ++c) {
            float4 a = xv[c], b = wv[c];
            acc += a.x*b.x + a.y*b.y + a.z*b.z + a.w*b.w;
        }
        int p = p0 + ps;
        if (u < 36) {
            int aidx = u >> 2, r = u & 3;
            deltas[(size_t)(p*9 + aidx)*4 + r] = acc + regb[aidx*8 + r];
        } else if (u < 45) {
            float z = acc + clsb[u-36];
            s_arr[p*9 + (u-36)] = 1.f/(1.f + expf(-z));
        } else {
            lm_out[(size_t)p*54 + (u-45)] = acc + lmb[u-45];
        }
    }
}

__global__ __launch_bounds__(256) void decode_kernel(
    const float* __restrict__ deltas, float* __restrict__ s_arr,
    float* __restrict__ boxes, float* __restrict__ anch_out,
    unsigned long long* __restrict__ slot)
{
    int n = blockIdx.x*256 + threadIdx.x;
    if (n < 8) slot[n] = 0ull;
    if (n >= NANCH) return;
    int p = n / 9, a = n - 9*p;
    int y = p / FW, x = p - FW*y;
    float cx = (x + 0.5f)*STRIDE, cy = (y + 0.5f)*STRIDE;
    const float rr[3] = {0.5f, 1.f, 2.f};
    const float ss[3] = {8.f, 16.f, 32.f};
    float r = rr[a/3], sv = ss[a - (a/3)*3];
    float h  = sqrtf(sv*sv/r)*STRIDE;
    float wv = h * r;
    float x1a = cx - wv*0.5f, y1a = cy - h*0.5f;
    float x2a = cx + wv*0.5f, y2a = cy + h*0.5f;
    float4 av = {x1a, y1a, x2a, y2a};
    *(float4*)(anch_out + (size_t)4*n) = av;
    bool valid = (x1a >= 0.f) && (y1a >= 0.f) && (x2a <= IMG) && (y2a <= IMG);

    float4 d = *(const float4*)(deltas + (size_t)4*n);
    float px = cx + wv*d.x, py = cy + h*d.y;
    float pw = wv*expf(d.z), ph = h*expf(d.w);
    float bx1 = px - pw*0.5f, by1 = py - ph*0.5f;
    float4 b;
    b.x = fminf(fmaxf(bx1, 0.f), IMG);
    b.y = fminf(fmaxf(by1, 0.f), IMG);
    b.z = fminf(fmaxf(bx1 + pw, 0.f), IMG);
    b.w = fminf(fmaxf(by1 + ph, 0.f), IMG);
    *(float4*)(boxes + (size_t)4*n) = b;
    if (!valid) s_arr[n] = -1.f;
}

// ---------------------------------------------------------------------------
extern "C" void kernel_launch(void* const* d_in, const int* in_sizes, int n_in,
                              void* d_out, int out_size, void* d_ws, size_t ws_size,
                              hipStream_t stream)
{
    const float* f    = (const float*)d_in[0];
    const float* c1w  = (const float*)d_in[2];
    const float* c1b  = (const float*)d_in[3];
    const float* regw = (const float*)d_in[4];
    const float* regb = (const float*)d_in[5];
    const float* clsw = (const float*)d_in[6];
    const float* clsb = (const float*)d_in[7];
    const float* lmw  = (const float*)d_in[8];
    const float* lmb  = (const float*)d_in[9];

    float* out      = (float*)d_out;
    float* rois     = out;
    float* lm_out   = out + 24;
    float* anch_out = out + 24 + (size_t)NPOS*54;

    char* ws = (char*)d_ws;

    if (ws_size >= 67395840ull) {
        unsigned long long* slot = (unsigned long long*)ws;       // 8 x u64
        unsigned short* whh = (unsigned short*)(ws + 256);        //   131,072
        unsigned short* whl = (unsigned short*)(ws + 131328);     //   131,072
        unsigned short* fph = (unsigned short*)(ws + 262400);     // 26,873,856
        unsigned short* wth = (unsigned short*)(ws + 27136256);   //  4,718,592
        unsigned short* wtl = (unsigned short*)(ws + 31854848);   //  4,718,592
        unsigned short* xhh = (unsigned short*)(ws + 36573440);   // 26,214,400
        float* boxes  = (float*)(ws + 62787840);                  //  3,686,400
        float* s_arr  = (float*)(ws + 66474240);                  //    921,600

        prep_kernel<<<15682, 256, 0, stream>>>(f, c1w, regw, clsw, lmw,
                                               fph, wth, wtl, whh, whl);
        conv1_mfma_kernel<<<800, 128, 0, stream>>>(fph, wth, wtl, c1b, xhh);
        heads_mfma_kernel<<<200, 256, 0, stream>>>(xhh, whh, whl, regb, clsb, lmb,
                                                   lm_out, boxes, anch_out, s_arr, slot);
        for (int k = 0; k < 6; ++k)
            nms_iter_kernel<<<NANCH/256, 256, 0, stream>>>(boxes, s_arr, slot, k);
        nms_fin_kernel<<<1, 64, 0, stream>>>(boxes, slot, rois);
    } else {
        unsigned long long* slot = (unsigned long long*)ws;
        float* wT     = (float*)(ws + 256);
        float* boxes  = (float*)(ws + 256 + 202752);
        float* deltas = (float*)(ws + 256 + 202752 + 3686400);
        float* s_arr  = (float*)(ws + 256 + 202752 + 2*3686400);
        float* x      = (float*)(ws + 256 + 202752 + 2*3686400 + 921600);

        wprep_kernel<<<(99*512 + 255)/256, 256, 0, stream>>>(regw, clsw, lmw, wT);
        conv1_kernel<<<dim3(8, 400), 256, 0, stream>>>(f, c1w, c1b, x);
        heads_kernel<<<NPOS/16, 256, 0, stream>>>(x, wT, regb, clsb, lmb,
                                                  lm_out, deltas, s_arr);
        decode_kernel<<<NANCH/256, 256, 0, stream>>>(deltas, s_arr, boxes,
                                                     anch_out, slot);
        for (int k = 0; k < 6; ++k)
            nms_iter_kernel<<<NANCH/256, 256, 0, stream>>>(boxes, s_arr, slot, k);
        nms_fin_kernel<<<1, 64, 0, stream>>>(boxes, slot, rois);
    }
}

// Round 5
// 433.547 us; speedup vs baseline: 1.7024x; 1.7024x over previous
//
#include <hip/hip_runtime.h>
#include <math.h>

#define FH 160
#define FW 160
#define NPOS (FH*FW)        // 25600
#define NANCH (NPOS*9)      // 230400
#define IMG 2560.0f
#define STRIDE 16.0f

typedef __attribute__((ext_vector_type(8))) _Float16 half8;
typedef __attribute__((ext_vector_type(4))) float f32x4;

__device__ __forceinline__ unsigned short f2h(float v) {
    _Float16 h = (_Float16)v;          // RNE
    return *(unsigned short*)&h;
}
__device__ __forceinline__ void g2l16(void* lds, const void* g) {
    __builtin_amdgcn_global_load_lds(
        (const __attribute__((address_space(1))) void*)g,
        (__attribute__((address_space(3))) void*)lds, 16, 0, 0);
}

// ---------------------------------------------------------------------------
// prep: fused — features pad+fp16 [162][162][512]; conv1 W transpose to
// [512 oc][4608 k] fp16; head W pack to [128 u][512 c] fp16.
// ---------------------------------------------------------------------------
__global__ __launch_bounds__(256) void prep_kernel(
    const float* __restrict__ f, const float* __restrict__ w,
    const float* __restrict__ regw, const float* __restrict__ clsw,
    const float* __restrict__ lmw,
    unsigned short* __restrict__ fph, unsigned short* __restrict__ wt,
    unsigned short* __restrict__ wh)
{
    __shared__ float tile[32][33];
    const int bid = blockIdx.x, t = threadIdx.x;
    if (bid < 13122) {                      // features: 162*162*128 threads
        int idx = bid*256 + t;
        int c4 = (idx & 127) << 2;
        int rest = idx >> 7;
        int x = rest % 162, y = rest / 162;
        float4 v = make_float4(0.f, 0.f, 0.f, 0.f);
        if (y > 0 && y < 161 && x > 0 && x < 161)
            v = *(const float4*)(f + ((size_t)((y-1)*FW + (x-1)) << 9) + c4);
        ushort4 h;
        h.x = f2h(v.x); h.y = f2h(v.y); h.z = f2h(v.z); h.w = f2h(v.w);
        *(ushort4*)(fph + ((size_t)(y*162 + x) << 9) + c4) = h;
    } else if (bid < 15426) {               // conv1 W: 144 x 16 transpose tiles
        int b = bid - 13122;
        int k0 = (b % 144)*32, oc0 = (b / 144)*32;
        int c = t & 31, r8 = t >> 5;
#pragma unroll
        for (int i = 0; i < 4; ++i) {
            int r = r8 + i*8;
            tile[c][r] = w[(size_t)(k0 + r)*512 + oc0 + c];
        }
        __syncthreads();
#pragma unroll
        for (int i = 0; i < 4; ++i) {
            int orow = r8 + i*8, kcol = c;
            wt[(size_t)(oc0 + orow)*4608 + k0 + kcol] = f2h(tile[orow][kcol]);
        }
    } else {                                // head W pack: 128x512
        int i = (bid - 15426)*256 + t;
        int u = i >> 9, c = i & 511;
        float v = 0.f;
        if (u < 36)      v = regw[c*72 + (u>>2)*8 + (u&3)];
        else if (u < 45) v = clsw[c*9 + (u-36)];
        else if (u < 99) v = lmw[c*54 + (u-45)];
        wh[i] = f2h(v);
    }
}

// ---------------------------------------------------------------------------
// conv1 MFMA fp16 single-term. Block 256 thr (2x2 waves), BM=BN=128, BK=64,
// wave tile 64x64. LDS 32KB -> 5 blocks/CU = 20 waves/CU (R4 lesson:
// occupancy dominates; R3 structure + fp16 halves both MFMA count and B
// traffic). Conflict-free 3-bit XOR k-chunk swizzle (R4-verified, 0 conflicts)
// applied via global-address permutation (g2l LDS addr is forced linear).
// XCD stripe: bid&7 -> oc-panel per XCD (B panel 1.2MB < 4MB L2).
// ---------------------------------------------------------------------------
__global__ __launch_bounds__(256) void conv1_mfma_kernel(
    const unsigned short* __restrict__ fph, const unsigned short* __restrict__ wt,
    const float* __restrict__ bias, unsigned short* __restrict__ xh)
{
    __shared__ unsigned short As[128*64];
    __shared__ unsigned short Bs[128*64];
    const int tid  = threadIdx.x;
    const int lane = tid & 63;
    const int wi   = (tid >> 7) & 1;
    const int wj   = (tid >> 6) & 1;
    const int bid  = blockIdx.x;
    const int xcd  = bid & 7, sl = bid >> 3;
    const int oc0  = (xcd & 3) * 128;
    const int pt   = (xcd >> 2) * 100 + sl;
    const int ty = pt / 5, tx = pt - ty*5;
    const int y0 = ty*4, x0 = tx*32;

    const int srow = tid >> 3;               // 0..31
    const int kswz = (((tid & 7) ^ (srow & 7)) << 3);
    const int quad = lane >> 4, fr = lane & 15;

    f32x4 acc[4][4] = {};
    const size_t bBase = (size_t)(oc0 + srow)*4608 + kswz;

    for (int tap = 0; tap < 9; ++tap) {
        const int ky = tap/3, kx = tap - (tap/3)*3;
        const size_t aBase = ((size_t)((y0 + ky)*162 + (x0 + srow + kx)) << 9) + kswz;
        const size_t bTap  = bBase + tap*512;
        for (int icb = 0; icb < 512; icb += 64) {
#pragma unroll
            for (int r = 0; r < 4; ++r) {
                // A rows 32r..32r+31 == y offset r, x = srow
                g2l16(As + tid*8 + r*2048, fph + aBase + (size_t)r*162*512 + icb);
                g2l16(Bs + tid*8 + r*2048, wt  + bTap  + (size_t)r*32*4608 + icb);
            }
            __syncthreads();
#pragma unroll
            for (int kk = 0; kk < 2; ++kk) {
                const int sa = ((kk*4 + quad) ^ (fr & 7)) << 3;
                half8 a[4], b[4];
#pragma unroll
                for (int i = 0; i < 4; ++i) {
                    a[i] = *(const half8*)(As + (wi*64 + i*16 + fr)*64 + sa);
                    b[i] = *(const half8*)(Bs + (wj*64 + i*16 + fr)*64 + sa);
                }
#pragma unroll
                for (int i = 0; i < 4; ++i)
#pragma unroll
                    for (int j = 0; j < 4; ++j)
                        acc[i][j] = __builtin_amdgcn_mfma_f32_16x16x32_f16(a[i], b[j], acc[i][j], 0, 0, 0);
            }
            __syncthreads();
        }
    }

    // epilogue: C/D col=lane&15 (oc), row=(lane>>4)*4+reg (pos); ReLU -> fp16
#pragma unroll
    for (int i = 0; i < 4; ++i) {
#pragma unroll
        for (int r = 0; r < 4; ++r) {
            int mi = wi*64 + i*16 + quad*4 + r;
            int p = (y0 + (mi >> 5))*FW + x0 + (mi & 31);
#pragma unroll
            for (int j = 0; j < 4; ++j) {
                int col = oc0 + wj*64 + j*16 + fr;
                float v = acc[i][j][r] + bias[col];
                xh[(size_t)p*512 + col] = f2h(v > 0.f ? v : 0.f);
            }
        }
    }
}

// ---------------------------------------------------------------------------
// heads MFMA fp16 + fused decode/anchors. M=25600, N=128(99 used), K=512.
// Epilogue: deltas+cls -> LDS, then 128x9 anchor decode writes boxes,
// anch_out, masked scores. Block 0 zeroes NMS slots.
// ---------------------------------------------------------------------------
__global__ __launch_bounds__(256) void heads_mfma_kernel(
    const unsigned short* __restrict__ xh, const unsigned short* __restrict__ wh,
    const float* __restrict__ regb, const float* __restrict__ clsb,
    const float* __restrict__ lmb,
    float* __restrict__ lm_out, float* __restrict__ boxes,
    float* __restrict__ anch_out, float* __restrict__ s_arr,
    unsigned long long* __restrict__ slot)
{
    __shared__ unsigned short As[128*64];
    __shared__ unsigned short Bs[128*64];
    __shared__ float sdel[128][40];
    __shared__ float scls[128][12];
    const int tid  = threadIdx.x;
    const int lane = tid & 63;
    const int wi   = (tid >> 7) & 1;
    const int wj   = (tid >> 6) & 1;
    const int p0   = blockIdx.x * 128;

    const int srow = tid >> 3;
    const int kswz = (((tid & 7) ^ (srow & 7)) << 3);
    const int quad = lane >> 4, fr = lane & 15;
    f32x4 acc[4][4] = {};

    const size_t aOfs = ((size_t)(p0 + srow) << 9) + kswz;
    const size_t bOfs = ((size_t)srow << 9) + kswz;

    for (int icb = 0; icb < 512; icb += 64) {
#pragma unroll
        for (int r = 0; r < 4; ++r) {
            g2l16(As + tid*8 + r*2048, xh + aOfs + (size_t)r*32*512 + icb);
            g2l16(Bs + tid*8 + r*2048, wh + bOfs + (size_t)r*32*512 + icb);
        }
        __syncthreads();
#pragma unroll
        for (int kk = 0; kk < 2; ++kk) {
            const int sa = ((kk*4 + quad) ^ (fr & 7)) << 3;
            half8 a[4], b[4];
#pragma unroll
            for (int i = 0; i < 4; ++i) {
                a[i] = *(const half8*)(As + (wi*64 + i*16 + fr)*64 + sa);
                b[i] = *(const half8*)(Bs + (wj*64 + i*16 + fr)*64 + sa);
            }
#pragma unroll
            for (int i = 0; i < 4; ++i)
#pragma unroll
                for (int j = 0; j < 4; ++j)
                    acc[i][j] = __builtin_amdgcn_mfma_f32_16x16x32_f16(a[i], b[j], acc[i][j], 0, 0, 0);
        }
        __syncthreads();
    }

#pragma unroll
    for (int i = 0; i < 4; ++i) {
#pragma unroll
        for (int r = 0; r < 4; ++r) {
            int pl = wi*64 + i*16 + quad*4 + r;
            int p = p0 + pl;
#pragma unroll
            for (int j = 0; j < 4; ++j) {
                int u = wj*64 + j*16 + fr;
                float v = acc[i][j][r];
                if (u < 36) {
                    sdel[pl][u] = v + regb[(u>>2)*8 + (u&3)];
                } else if (u < 45) {
                    float z = v + clsb[u-36];
                    scls[pl][u-36] = 1.f/(1.f + expf(-z));
                } else if (u < 99) {
                    lm_out[(size_t)p*54 + (u-45)] = v + lmb[u-45];
                }
            }
        }
    }
    if (blockIdx.x == 0 && tid < 8) slot[tid] = 0ull;
    __syncthreads();

    for (int t = tid; t < 128*9; t += 256) {
        int pl = t / 9, a = t - pl*9;
        int p = p0 + pl;
        int y = p / FW, x = p - FW*y;
        float cx = (x + 0.5f)*STRIDE, cy = (y + 0.5f)*STRIDE;
        const float rr[3] = {0.5f, 1.f, 2.f};
        const float ss[3] = {8.f, 16.f, 32.f};
        float r = rr[a/3], sv = ss[a - (a/3)*3];
        float h  = sqrtf(sv*sv/r)*STRIDE;
        float wvv = h * r;
        float x1a = cx - wvv*0.5f, y1a = cy - h*0.5f;
        float x2a = cx + wvv*0.5f, y2a = cy + h*0.5f;
        size_t n = (size_t)p*9 + a;
        float4 av = {x1a, y1a, x2a, y2a};
        *(float4*)(anch_out + 4*n) = av;
        bool valid = (x1a >= 0.f) && (y1a >= 0.f) && (x2a <= IMG) && (y2a <= IMG);

        float dx = sdel[pl][a*4+0], dy = sdel[pl][a*4+1];
        float dw = sdel[pl][a*4+2], dh = sdel[pl][a*4+3];
        float px = cx + wvv*dx, py = cy + h*dy;
        float pw = wvv*expf(dw), ph = h*expf(dh);
        float bx1 = px - pw*0.5f, by1 = py - ph*0.5f;
        float4 b;
        b.x = fminf(fmaxf(bx1, 0.f), IMG);
        b.y = fminf(fmaxf(by1, 0.f), IMG);
        b.z = fminf(fmaxf(bx1 + pw, 0.f), IMG);
        b.w = fminf(fmaxf(by1 + ph, 0.f), IMG);
        *(float4*)(boxes + 4*n) = b;
        s_arr[n] = valid ? scls[pl][a] : -1.f;
    }
}

// ---------------------------------------------------------------------------
// NMS round k: suppress vs slot[k-1] winner, argmax into slot[k].
// Per-wave shuffle reduce -> per-block LDS reduce -> ONE atomic per block
// (900/round instead of 3600 same-address wave atomics).
// ---------------------------------------------------------------------------
__global__ __launch_bounds__(256) void nms_iter_kernel(
    const float* __restrict__ boxes, float* __restrict__ s_arr,
    unsigned long long* __restrict__ slot, int k)
{
    __shared__ unsigned long long red[4];
    int n = blockIdx.x*256 + threadIdx.x;
    float s = s_arr[n];
    if (k > 0) {
        unsigned int wn = ~(unsigned int)(slot[k-1] & 0xFFFFFFFFull);
        float4 wb = *(const float4*)(boxes + (size_t)4*wn);
        float4 b  = *(const float4*)(boxes + (size_t)4*n);
        float ix = fminf(wb.z, b.z) - fmaxf(wb.x, b.x);
        float iy = fminf(wb.w, b.w) - fmaxf(wb.y, b.y);
        float inter = fmaxf(ix, 0.f)*fmaxf(iy, 0.f);
        float a1 = (wb.z-wb.x)*(wb.w-wb.y);
        float a2 = (b.z-b.x)*(b.w-b.y);
        float iou = inter/(a1 + a2 - inter + 1e-9f);
        if (iou > 0.5f) { s = -1.f; s_arr[n] = -1.f; }
    }
    unsigned int bu = __float_as_uint(s);
    unsigned int key = (bu & 0x80000000u) ? ~bu : (bu | 0x80000000u);
    unsigned long long packed =
        ((unsigned long long)key << 32) | (unsigned int)~(unsigned int)n;
#pragma unroll
    for (int off = 32; off > 0; off >>= 1) {
        unsigned long long o = __shfl_xor(packed, off, 64);
        packed = packed > o ? packed : o;
    }
    if ((threadIdx.x & 63) == 0) red[threadIdx.x >> 6] = packed;
    __syncthreads();
    if (threadIdx.x == 0) {
        unsigned long long m = red[0];
        m = m > red[1] ? m : red[1];
        m = m > red[2] ? m : red[2];
        m = m > red[3] ? m : red[3];
        atomicMax(&slot[k], m);
    }
}

__global__ void nms_fin_kernel(
    const float* __restrict__ boxes,
    const unsigned long long* __restrict__ slot, float* __restrict__ rois)
{
    int t = threadIdx.x;
    if (t < 6) {
        unsigned int n = ~(unsigned int)(slot[t] & 0xFFFFFFFFull);
        float4 b = *(const float4*)(boxes + (size_t)4*n);
        *(float4*)(rois + 4*t) = b;
    }
}

// ---------------------------------------------------------------------------
// fallback fp32 path kernels (known-good round-1 structure)
// ---------------------------------------------------------------------------
__global__ __launch_bounds__(256) void conv1_kernel(
    const float* __restrict__ f, const float* __restrict__ w,
    const float* __restrict__ bias, float* __restrict__ xout)
{
    __shared__ float As2[32][66];
    __shared__ float Bs2[32][66];
    const int tid = threadIdx.x;
    const int nt = blockIdx.x;
    const int mt = blockIdx.y;
    const int p0 = mt*64, oc0 = nt*64;
    const int tm = tid & 15, tn = tid >> 4;
    const int kA = tid & 31, mA = tid >> 5;
    const int nB = tid & 63, kB = tid >> 6;
    int yv[8], xv[8];
#pragma unroll
    for (int it = 0; it < 8; ++it) {
        int p = p0 + mA + it*8;
        yv[it] = p / FW;
        xv[it] = p - yv[it]*FW;
    }
    float acc[4][4] = {};
    for (int tap = 0; tap < 9; ++tap) {
        const int ky = tap/3 - 1, kx = tap%3 - 1;
        for (int icb = 0; icb < 512; icb += 32) {
#pragma unroll
            for (int it = 0; it < 8; ++it) {
                int yy = yv[it] + ky, xx = xv[it] + kx;
                float v = 0.f;
                if ((unsigned)yy < (unsigned)FH && (unsigned)xx < (unsigned)FW)
                    v = f[(((yy*FW)+xx)<<9) + icb + kA];
                As2[kA][mA + it*8] = v;
            }
            const float* wp = w + ((size_t)(tap*512 + icb + kB))*512 + oc0 + nB;
#pragma unroll
            for (int it = 0; it < 8; ++it)
                Bs2[kB + it*4][nB] = wp[(size_t)it*4*512];
            __syncthreads();
#pragma unroll 8
            for (int kk = 0; kk < 32; ++kk) {
                float a0 = As2[kk][4*tm+0], a1 = As2[kk][4*tm+1],
                      a2 = As2[kk][4*tm+2], a3 = As2[kk][4*tm+3];
                float b0 = Bs2[kk][4*tn+0], b1 = Bs2[kk][4*tn+1],
                      b2 = Bs2[kk][4*tn+2], b3 = Bs2[kk][4*tn+3];
                acc[0][0] += a0*b0; acc[0][1] += a0*b1; acc[0][2] += a0*b2; acc[0][3] += a0*b3;
                acc[1][0] += a1*b0; acc[1][1] += a1*b1; acc[1][2] += a1*b2; acc[1][3] += a1*b3;
                acc[2][0] += a2*b0; acc[2][1] += a2*b1; acc[2][2] += a2*b2; acc[2][3] += a2*b3;
                acc[3][0] += a3*b0; acc[3][1] += a3*b1; acc[3][2] += a3*b2; acc[3][3] += a3*b3;
            }
            __syncthreads();
        }
    }
#pragma unroll
    for (int i = 0; i < 4; ++i) {
        int p = p0 + 4*tm + i;
        float4 o;
        float* op = &o.x;
#pragma unroll
        for (int j = 0; j < 4; ++j) {
            float v = acc[i][j] + bias[oc0 + 4*tn + j];
            op[j] = v > 0.f ? v : 0.f;
        }
        *(float4*)(xout + (size_t)p*512 + oc0 + 4*tn) = o;
    }
}

__global__ __launch_bounds__(256) void wprep_kernel(
    const float* __restrict__ regw, const float* __restrict__ clsw,
    const float* __restrict__ lmw, float* __restrict__ wT)
{
    int i = blockIdx.x*256 + threadIdx.x;
    if (i >= 99*512) return;
    int u = i >> 9, c = i & 511;
    float v;
    if (u < 36)      v = regw[c*72 + (u>>2)*8 + (u&3)];
    else if (u < 45) v = clsw[c*9 + (u-36)];
    else             v = lmw[c*54 + (u-45)];
    wT[i] = v;
}

__global__ __launch_bounds__(256) void heads_kernel(
    const float* __restrict__ x, const float* __restrict__ wT,
    const float* __restrict__ regb, const float* __restrict__ clsb,
    const float* __restrict__ lmb,
    float* __restrict__ lm_out, float* __restrict__ deltas,
    float* __restrict__ s_arr)
{
    __shared__ float xs[16*516];
    const int p0 = blockIdx.x * 16;
    const float4* src = (const float4*)(x + (size_t)p0*512);
    for (int i = threadIdx.x; i < 16*128; i += 256) {
        int row = i >> 7, c4 = i & 127;
        *(float4*)(xs + row*516 + c4*4) = src[row*128 + c4];
    }
    __syncthreads();
    for (int oi = threadIdx.x; oi < 99*16; oi += 256) {
        int ps = oi & 15, u = oi >> 4;
        const float4* wv = (const float4*)(wT + (u << 9));
        const float4* xv = (const float4*)(xs + ps*516);
        float acc = 0.f;
#pragma unroll 4
        for (int c = 0; c < 128; ++c) {
            float4 a = xv[c], b = wv[c];
            acc += a.x*b.x + a.y*b.y + a.z*b.z + a.w*b.w;
        }
        int p = p0 + ps;
        if (u < 36) {
            int aidx = u >> 2, r = u & 3;
            deltas[(size_t)(p*9 + aidx)*4 + r] = acc + regb[aidx*8 + r];
        } else if (u < 45) {
            float z = acc + clsb[u-36];
            s_arr[p*9 + (u-36)] = 1.f/(1.f + expf(-z));
        } else {
            lm_out[(size_t)p*54 + (u-45)] = acc + lmb[u-45];
        }
    }
}

__global__ __launch_bounds__(256) void decode_kernel(
    const float* __restrict__ deltas, float* __restrict__ s_arr,
    float* __restrict__ boxes, float* __restrict__ anch_out,
    unsigned long long* __restrict__ slot)
{
    int n = blockIdx.x*256 + threadIdx.x;
    if (n < 8) slot[n] = 0ull;
    if (n >= NANCH) return;
    int p = n / 9, a = n - 9*p;
    int y = p / FW, x = p - FW*y;
    float cx = (x + 0.5f)*STRIDE, cy = (y + 0.5f)*STRIDE;
    const float rr[3] = {0.5f, 1.f, 2.f};
    const float ss[3] = {8.f, 16.f, 32.f};
    float r = rr[a/3], sv = ss[a - (a/3)*3];
    float h  = sqrtf(sv*sv/r)*STRIDE;
    float wv = h * r;
    float x1a = cx - wv*0.5f, y1a = cy - h*0.5f;
    float x2a = cx + wv*0.5f, y2a = cy + h*0.5f;
    float4 av = {x1a, y1a, x2a, y2a};
    *(float4*)(anch_out + (size_t)4*n) = av;
    bool valid = (x1a >= 0.f) && (y1a >= 0.f) && (x2a <= IMG) && (y2a <= IMG);

    float4 d = *(const float4*)(deltas + (size_t)4*n);
    float px = cx + wv*d.x, py = cy + h*d.y;
    float pw = wv*expf(d.z), ph = h*expf(d.w);
    float bx1 = px - pw*0.5f, by1 = py - ph*0.5f;
    float4 b;
    b.x = fminf(fmaxf(bx1, 0.f), IMG);
    b.y = fminf(fmaxf(by1, 0.f), IMG);
    b.z = fminf(fmaxf(bx1 + pw, 0.f), IMG);
    b.w = fminf(fmaxf(by1 + ph, 0.f), IMG);
    *(float4*)(boxes + (size_t)4*n) = b;
    if (!valid) s_arr[n] = -1.f;
}

// ---------------------------------------------------------------------------
extern "C" void kernel_launch(void* const* d_in, const int* in_sizes, int n_in,
                              void* d_out, int out_size, void* d_ws, size_t ws_size,
                              hipStream_t stream)
{
    const float* f    = (const float*)d_in[0];
    const float* c1w  = (const float*)d_in[2];
    const float* c1b  = (const float*)d_in[3];
    const float* regw = (const float*)d_in[4];
    const float* regb = (const float*)d_in[5];
    const float* clsw = (const float*)d_in[6];
    const float* clsb = (const float*)d_in[7];
    const float* lmw  = (const float*)d_in[8];
    const float* lmb  = (const float*)d_in[9];

    float* out      = (float*)d_out;
    float* rois     = out;
    float* lm_out   = out + 24;
    float* anch_out = out + 24 + (size_t)NPOS*54;

    char* ws = (char*)d_ws;

    if (ws_size >= 62546176ull) {
        unsigned long long* slot = (unsigned long long*)ws;       // 8 x u64
        unsigned short* wh  = (unsigned short*)(ws + 256);        //    131,072
        unsigned short* fph = (unsigned short*)(ws + 131328);     // 26,873,856
        unsigned short* wt  = (unsigned short*)(ws + 27005184);   //  4,718,592
        unsigned short* xh  = (unsigned short*)(ws + 31723776);   // 26,214,400
        float* boxes  = (float*)(ws + 57938176);                  //  3,686,400
        float* s_arr  = (float*)(ws + 61624576);                  //    921,600

        prep_kernel<<<15682, 256, 0, stream>>>(f, c1w, regw, clsw, lmw,
                                               fph, wt, wh);
        conv1_mfma_kernel<<<800, 256, 0, stream>>>(fph, wt, c1b, xh);
        heads_mfma_kernel<<<200, 256, 0, stream>>>(xh, wh, regb, clsb, lmb,
                                                   lm_out, boxes, anch_out, s_arr, slot);
        for (int k = 0; k < 6; ++k)
            nms_iter_kernel<<<NANCH/256, 256, 0, stream>>>(boxes, s_arr, slot, k);
        nms_fin_kernel<<<1, 64, 0, stream>>>(boxes, slot, rois);
    } else {
        unsigned long long* slot = (unsigned long long*)ws;
        float* wT     = (float*)(ws + 256);
        float* boxes  = (float*)(ws + 256 + 202752);
        float* deltas = (float*)(ws + 256 + 202752 + 3686400);
        float* s_arr  = (float*)(ws + 256 + 202752 + 2*3686400);
        float* x      = (float*)(ws + 256 + 202752 + 2*3686400 + 921600);

        wprep_kernel<<<(99*512 + 255)/256, 256, 0, stream>>>(regw, clsw, lmw, wT);
        conv1_kernel<<<dim3(8, 400), 256, 0, stream>>>(f, c1w, c1b, x);
        heads_kernel<<<NPOS/16, 256, 0, stream>>>(x, wT, regb, clsb, lmb,
                                                  lm_out, deltas, s_arr);
        decode_kernel<<<NANCH/256, 256, 0, stream>>>(deltas, s_arr, boxes,
                                                     anch_out, slot);
        for (int k = 0; k < 6; ++k)
            nms_iter_kernel<<<NANCH/256, 256, 0, stream>>>(boxes, s_arr, slot, k);
        nms_fin_kernel<<<1, 64, 0, stream>>>(boxes, slot, rois);
    }
}

// Round 6
// 388.500 us; speedup vs baseline: 1.8998x; 1.1160x over previous
//
#include <hip/hip_runtime.h>
#include <math.h>

#define FH 160
#define FW 160
#define NPOS (FH*FW)        // 25600
#define NANCH (NPOS*9)      // 230400
#define IMG 2560.0f
#define STRIDE 16.0f

typedef __attribute__((ext_vector_type(8))) _Float16 half8;
typedef __attribute__((ext_vector_type(4))) float f32x4;
typedef unsigned long long u64;

__device__ __forceinline__ unsigned short f2h(float v) {
    _Float16 h = (_Float16)v;          // RNE
    return *(unsigned short*)&h;
}
__device__ __forceinline__ void g2l16(void* lds, const void* g) {
    __builtin_amdgcn_global_load_lds(
        (const __attribute__((address_space(1))) void*)g,
        (__attribute__((address_space(3))) void*)lds, 16, 0, 0);
}
__device__ __forceinline__ u64 pack_key(float s, int n) {
    unsigned int bu = __float_as_uint(s);
    unsigned int key = (bu & 0x80000000u) ? ~bu : (bu | 0x80000000u);
    return ((u64)key << 32) | (unsigned int)~(unsigned int)n;
}
__device__ __forceinline__ u64 wave_max64(u64 v) {
#pragma unroll
    for (int off = 32; off > 0; off >>= 1) {
        u64 o = __shfl_xor(v, off, 64);
        v = v > o ? v : o;
    }
    return v;
}

// ---------------------------------------------------------------------------
// prep: fused — features pad+fp16 [162][162][512]; conv1 W transpose to
// [512 oc][4608 k] fp16; head W pack to [128 u][512 c] fp16.
// ---------------------------------------------------------------------------
__global__ __launch_bounds__(256) void prep_kernel(
    const float* __restrict__ f, const float* __restrict__ w,
    const float* __restrict__ regw, const float* __restrict__ clsw,
    const float* __restrict__ lmw,
    unsigned short* __restrict__ fph, unsigned short* __restrict__ wt,
    unsigned short* __restrict__ wh)
{
    __shared__ float tile[32][33];
    const int bid = blockIdx.x, t = threadIdx.x;
    if (bid < 13122) {                      // features: 162*162*128 threads
        int idx = bid*256 + t;
        int c4 = (idx & 127) << 2;
        int rest = idx >> 7;
        int x = rest % 162, y = rest / 162;
        float4 v = make_float4(0.f, 0.f, 0.f, 0.f);
        if (y > 0 && y < 161 && x > 0 && x < 161)
            v = *(const float4*)(f + ((size_t)((y-1)*FW + (x-1)) << 9) + c4);
        ushort4 h;
        h.x = f2h(v.x); h.y = f2h(v.y); h.z = f2h(v.z); h.w = f2h(v.w);
        *(ushort4*)(fph + ((size_t)(y*162 + x) << 9) + c4) = h;
    } else if (bid < 15426) {               // conv1 W: 144 x 16 transpose tiles
        int b = bid - 13122;
        int k0 = (b % 144)*32, oc0 = (b / 144)*32;
        int c = t & 31, r8 = t >> 5;
#pragma unroll
        for (int i = 0; i < 4; ++i) {
            int r = r8 + i*8;
            tile[c][r] = w[(size_t)(k0 + r)*512 + oc0 + c];
        }
        __syncthreads();
#pragma unroll
        for (int i = 0; i < 4; ++i) {
            int orow = r8 + i*8, kcol = c;
            wt[(size_t)(oc0 + orow)*4608 + k0 + kcol] = f2h(tile[orow][kcol]);
        }
    } else {                                // head W pack: 128x512
        int i = (bid - 15426)*256 + t;
        int u = i >> 9, c = i & 511;
        float v = 0.f;
        if (u < 36)      v = regw[c*72 + (u>>2)*8 + (u&3)];
        else if (u < 45) v = clsw[c*9 + (u-36)];
        else if (u < 99) v = lmw[c*54 + (u-45)];
        wh[i] = f2h(v);
    }
}

// ---------------------------------------------------------------------------
// conv1 MFMA fp16, BM=BN=128 BK=64, 256 thr (2x2 waves), wave tile 64x64.
// Unchanged from R5 (179 us, MfmaUtil 29%, 0 conflicts — m97-plateau bound).
// ---------------------------------------------------------------------------
__global__ __launch_bounds__(256) void conv1_mfma_kernel(
    const unsigned short* __restrict__ fph, const unsigned short* __restrict__ wt,
    const float* __restrict__ bias, unsigned short* __restrict__ xh)
{
    __shared__ unsigned short As[128*64];
    __shared__ unsigned short Bs[128*64];
    const int tid  = threadIdx.x;
    const int lane = tid & 63;
    const int wi   = (tid >> 7) & 1;
    const int wj   = (tid >> 6) & 1;
    const int bid  = blockIdx.x;
    const int xcd  = bid & 7, sl = bid >> 3;
    const int oc0  = (xcd & 3) * 128;
    const int pt   = (xcd >> 2) * 100 + sl;
    const int ty = pt / 5, tx = pt - ty*5;
    const int y0 = ty*4, x0 = tx*32;

    const int srow = tid >> 3;               // 0..31
    const int kswz = (((tid & 7) ^ (srow & 7)) << 3);
    const int quad = lane >> 4, fr = lane & 15;

    f32x4 acc[4][4] = {};
    const size_t bBase = (size_t)(oc0 + srow)*4608 + kswz;

    for (int tap = 0; tap < 9; ++tap) {
        const int ky = tap/3, kx = tap - (tap/3)*3;
        const size_t aBase = ((size_t)((y0 + ky)*162 + (x0 + srow + kx)) << 9) + kswz;
        const size_t bTap  = bBase + tap*512;
        for (int icb = 0; icb < 512; icb += 64) {
#pragma unroll
            for (int r = 0; r < 4; ++r) {
                g2l16(As + tid*8 + r*2048, fph + aBase + (size_t)r*162*512 + icb);
                g2l16(Bs + tid*8 + r*2048, wt  + bTap  + (size_t)r*32*4608 + icb);
            }
            __syncthreads();
#pragma unroll
            for (int kk = 0; kk < 2; ++kk) {
                const int sa = ((kk*4 + quad) ^ (fr & 7)) << 3;
                half8 a[4], b[4];
#pragma unroll
                for (int i = 0; i < 4; ++i) {
                    a[i] = *(const half8*)(As + (wi*64 + i*16 + fr)*64 + sa);
                    b[i] = *(const half8*)(Bs + (wj*64 + i*16 + fr)*64 + sa);
                }
#pragma unroll
                for (int i = 0; i < 4; ++i)
#pragma unroll
                    for (int j = 0; j < 4; ++j)
                        acc[i][j] = __builtin_amdgcn_mfma_f32_16x16x32_f16(a[i], b[j], acc[i][j], 0, 0, 0);
            }
            __syncthreads();
        }
    }

#pragma unroll
    for (int i = 0; i < 4; ++i) {
#pragma unroll
        for (int r = 0; r < 4; ++r) {
            int mi = wi*64 + i*16 + quad*4 + r;
            int p = (y0 + (mi >> 5))*FW + x0 + (mi & 31);
#pragma unroll
            for (int j = 0; j < 4; ++j) {
                int col = oc0 + wj*64 + j*16 + fr;
                float v = acc[i][j][r] + bias[col];
                xh[(size_t)p*512 + col] = f2h(v > 0.f ? v : 0.f);
            }
        }
    }
}

// ---------------------------------------------------------------------------
// heads MFMA fp16 + fused decode/anchors + per-block NMS seed max.
// LDS: union overlays epilogue buffers onto the GEMM staging buffers
// (32.8KB total -> 4 blocks/CU instead of 2). Each block covers 128
// positions = anchors [1152b, 1152(b+1)) and writes blockmax[b] = packed
// max (sortable score, ~index) over them — NMS round 0 comes for free.
// ---------------------------------------------------------------------------
__global__ __launch_bounds__(256) void heads_mfma_kernel(
    const unsigned short* __restrict__ xh, const unsigned short* __restrict__ wh,
    const float* __restrict__ regb, const float* __restrict__ clsb,
    const float* __restrict__ lmb,
    float* __restrict__ lm_out, float* __restrict__ boxes,
    float* __restrict__ anch_out, float* __restrict__ s_arr,
    u64* __restrict__ blockmax)
{
    __shared__ union SM {
        struct { unsigned short As[128*64]; unsigned short Bs[128*64]; } g;
        struct { float sdel[128][40]; float scls[128][12]; u64 red[8]; } e;
    } sm;
    unsigned short* As = sm.g.As;
    unsigned short* Bs = sm.g.Bs;
    const int tid  = threadIdx.x;
    const int lane = tid & 63;
    const int wi   = (tid >> 7) & 1;
    const int wj   = (tid >> 6) & 1;
    const int p0   = blockIdx.x * 128;

    const int srow = tid >> 3;
    const int kswz = (((tid & 7) ^ (srow & 7)) << 3);
    const int quad = lane >> 4, fr = lane & 15;
    f32x4 acc[4][4] = {};

    const size_t aOfs = ((size_t)(p0 + srow) << 9) + kswz;
    const size_t bOfs = ((size_t)srow << 9) + kswz;

    for (int icb = 0; icb < 512; icb += 64) {
#pragma unroll
        for (int r = 0; r < 4; ++r) {
            g2l16(As + tid*8 + r*2048, xh + aOfs + (size_t)r*32*512 + icb);
            g2l16(Bs + tid*8 + r*2048, wh + bOfs + (size_t)r*32*512 + icb);
        }
        __syncthreads();
#pragma unroll
        for (int kk = 0; kk < 2; ++kk) {
            const int sa = ((kk*4 + quad) ^ (fr & 7)) << 3;
            half8 a[4], b[4];
#pragma unroll
            for (int i = 0; i < 4; ++i) {
                a[i] = *(const half8*)(As + (wi*64 + i*16 + fr)*64 + sa);
                b[i] = *(const half8*)(Bs + (wj*64 + i*16 + fr)*64 + sa);
            }
#pragma unroll
            for (int i = 0; i < 4; ++i)
#pragma unroll
                for (int j = 0; j < 4; ++j)
                    acc[i][j] = __builtin_amdgcn_mfma_f32_16x16x32_f16(a[i], b[j], acc[i][j], 0, 0, 0);
        }
        __syncthreads();
    }
    // K-loop done; all LDS reads drained by the final barrier -> safe to
    // overlay the epilogue structs on As/Bs.

#pragma unroll
    for (int i = 0; i < 4; ++i) {
#pragma unroll
        for (int r = 0; r < 4; ++r) {
            int pl = wi*64 + i*16 + quad*4 + r;
            int p = p0 + pl;
#pragma unroll
            for (int j = 0; j < 4; ++j) {
                int u = wj*64 + j*16 + fr;
                float v = acc[i][j][r];
                if (u < 36) {
                    sm.e.sdel[pl][u] = v + regb[(u>>2)*8 + (u&3)];
                } else if (u < 45) {
                    float z = v + clsb[u-36];
                    sm.e.scls[pl][u-36] = 1.f/(1.f + expf(-z));
                } else if (u < 99) {
                    lm_out[(size_t)p*54 + (u-45)] = v + lmb[u-45];
                }
            }
        }
    }
    __syncthreads();

    u64 local = 0ull;
    for (int t = tid; t < 128*9; t += 256) {
        int pl = t / 9, a = t - pl*9;
        int p = p0 + pl;
        int y = p / FW, x = p - FW*y;
        float cx = (x + 0.5f)*STRIDE, cy = (y + 0.5f)*STRIDE;
        const float rr[3] = {0.5f, 1.f, 2.f};
        const float ss[3] = {8.f, 16.f, 32.f};
        float r = rr[a/3], sv = ss[a - (a/3)*3];
        float h  = sqrtf(sv*sv/r)*STRIDE;
        float wvv = h * r;
        float x1a = cx - wvv*0.5f, y1a = cy - h*0.5f;
        float x2a = cx + wvv*0.5f, y2a = cy + h*0.5f;
        size_t n = (size_t)p*9 + a;
        float4 av = {x1a, y1a, x2a, y2a};
        *(float4*)(anch_out + 4*n) = av;
        bool valid = (x1a >= 0.f) && (y1a >= 0.f) && (x2a <= IMG) && (y2a <= IMG);

        float dx = sm.e.sdel[pl][a*4+0], dy = sm.e.sdel[pl][a*4+1];
        float dw = sm.e.sdel[pl][a*4+2], dh = sm.e.sdel[pl][a*4+3];
        float px = cx + wvv*dx, py = cy + h*dy;
        float pw = wvv*expf(dw), ph = h*expf(dh);
        float bx1 = px - pw*0.5f, by1 = py - ph*0.5f;
        float4 b;
        b.x = fminf(fmaxf(bx1, 0.f), IMG);
        b.y = fminf(fmaxf(by1, 0.f), IMG);
        b.z = fminf(fmaxf(bx1 + pw, 0.f), IMG);
        b.w = fminf(fmaxf(by1 + ph, 0.f), IMG);
        *(float4*)(boxes + 4*n) = b;
        float s = valid ? sm.e.scls[pl][a] : -1.f;
        s_arr[n] = s;
        u64 pk = pack_key(s, (int)n);
        local = local > pk ? local : pk;
    }
    local = wave_max64(local);
    if ((tid & 63) == 0) sm.e.red[tid >> 6] = local;
    __syncthreads();
    if (tid == 0) {
        u64 m = sm.e.red[0];
        m = m > sm.e.red[1] ? m : sm.e.red[1];
        m = m > sm.e.red[2] ? m : sm.e.red[2];
        m = m > sm.e.red[3] ? m : sm.e.red[3];
        blockmax[blockIdx.x] = m;
    }
}

// ---------------------------------------------------------------------------
// NMS round k (k=1..5), zero atomics: every block redundantly reduces
// blockmax[0..199] -> winner of round k-1 (block 0 writes rois[k-1]),
// suppresses its own 1152 anchors, recomputes blockmax[b].
// ---------------------------------------------------------------------------
__global__ __launch_bounds__(256) void nms_supp_kernel(
    const float* __restrict__ boxes, float* __restrict__ s_arr,
    u64* __restrict__ blockmax, float* __restrict__ rois, int k)
{
    __shared__ u64 red[4];
    __shared__ u64 win_sh;
    const int tid = threadIdx.x;

    u64 v = (tid < 200) ? blockmax[tid] : 0ull;
    v = wave_max64(v);
    if ((tid & 63) == 0) red[tid >> 6] = v;
    __syncthreads();
    if (tid == 0) {
        u64 m = red[0];
        m = m > red[1] ? m : red[1];
        m = m > red[2] ? m : red[2];
        m = m > red[3] ? m : red[3];
        win_sh = m;
    }
    __syncthreads();
    const unsigned int wn = ~(unsigned int)(win_sh & 0xFFFFFFFFull);
    const float4 wb = *(const float4*)(boxes + (size_t)4*wn);
    if (blockIdx.x == 0 && tid == 0)
        *(float4*)(rois + 4*(k-1)) = wb;

    const float wa = (wb.z - wb.x)*(wb.w - wb.y);
    const int base = blockIdx.x * 1152;
    u64 local = 0ull;
    for (int i = tid; i < 1152; i += 256) {
        int n = base + i;
        float s = s_arr[n];
        float4 b = *(const float4*)(boxes + (size_t)4*n);
        float ix = fminf(wb.z, b.z) - fmaxf(wb.x, b.x);
        float iy = fminf(wb.w, b.w) - fmaxf(wb.y, b.y);
        float inter = fmaxf(ix, 0.f)*fmaxf(iy, 0.f);
        float a2 = (b.z - b.x)*(b.w - b.y);
        float iou = inter/(wa + a2 - inter + 1e-9f);
        if (iou > 0.5f && s > -1.f) { s = -1.f; s_arr[n] = -1.f; }
        u64 pk = pack_key(s, n);
        local = local > pk ? local : pk;
    }
    local = wave_max64(local);
    if ((tid & 63) == 0) red[tid >> 6] = local;
    __syncthreads();
    if (tid == 0) {
        u64 m = red[0];
        m = m > red[1] ? m : red[1];
        m = m > red[2] ? m : red[2];
        m = m > red[3] ? m : red[3];
        blockmax[blockIdx.x] = m;
    }
}

__global__ void nms_fin2_kernel(
    const float* __restrict__ boxes, const u64* __restrict__ blockmax,
    float* __restrict__ rois)
{
    __shared__ u64 red[4];
    const int tid = threadIdx.x;   // 256
    u64 v = (tid < 200) ? blockmax[tid] : 0ull;
    v = wave_max64(v);
    if ((tid & 63) == 0) red[tid >> 6] = v;
    __syncthreads();
    if (tid == 0) {
        u64 m = red[0];
        m = m > red[1] ? m : red[1];
        m = m > red[2] ? m : red[2];
        m = m > red[3] ? m : red[3];
        unsigned int wn = ~(unsigned int)(m & 0xFFFFFFFFull);
        *(float4*)(rois + 20) = *(const float4*)(boxes + (size_t)4*wn);
    }
}

// ---------------------------------------------------------------------------
// fallback fp32 path kernels (known-good round-1 structure)
// ---------------------------------------------------------------------------
__global__ __launch_bounds__(256) void conv1_kernel(
    const float* __restrict__ f, const float* __restrict__ w,
    const float* __restrict__ bias, float* __restrict__ xout)
{
    __shared__ float As2[32][66];
    __shared__ float Bs2[32][66];
    const int tid = threadIdx.x;
    const int nt = blockIdx.x;
    const int mt = blockIdx.y;
    const int p0 = mt*64, oc0 = nt*64;
    const int tm = tid & 15, tn = tid >> 4;
    const int kA = tid & 31, mA = tid >> 5;
    const int nB = tid & 63, kB = tid >> 6;
    int yv[8], xv[8];
#pragma unroll
    for (int it = 0; it < 8; ++it) {
        int p = p0 + mA + it*8;
        yv[it] = p / FW;
        xv[it] = p - yv[it]*FW;
    }
    float acc[4][4] = {};
    for (int tap = 0; tap < 9; ++tap) {
        const int ky = tap/3 - 1, kx = tap%3 - 1;
        for (int icb = 0; icb < 512; icb += 32) {
#pragma unroll
            for (int it = 0; it < 8; ++it) {
                int yy = yv[it] + ky, xx = xv[it] + kx;
                float v = 0.f;
                if ((unsigned)yy < (unsigned)FH && (unsigned)xx < (unsigned)FW)
                    v = f[(((yy*FW)+xx)<<9) + icb + kA];
                As2[kA][mA + it*8] = v;
            }
            const float* wp = w + ((size_t)(tap*512 + icb + kB))*512 + oc0 + nB;
#pragma unroll
            for (int it = 0; it < 8; ++it)
                Bs2[kB + it*4][nB] = wp[(size_t)it*4*512];
            __syncthreads();
#pragma unroll 8
            for (int kk = 0; kk < 32; ++kk) {
                float a0 = As2[kk][4*tm+0], a1 = As2[kk][4*tm+1],
                      a2 = As2[kk][4*tm+2], a3 = As2[kk][4*tm+3];
                float b0 = Bs2[kk][4*tn+0], b1 = Bs2[kk][4*tn+1],
                      b2 = Bs2[kk][4*tn+2], b3 = Bs2[kk][4*tn+3];
                acc[0][0] += a0*b0; acc[0][1] += a0*b1; acc[0][2] += a0*b2; acc[0][3] += a0*b3;
                acc[1][0] += a1*b0; acc[1][1] += a1*b1; acc[1][2] += a1*b2; acc[1][3] += a1*b3;
                acc[2][0] += a2*b0; acc[2][1] += a2*b1; acc[2][2] += a2*b2; acc[2][3] += a2*b3;
                acc[3][0] += a3*b0; acc[3][1] += a3*b1; acc[3][2] += a3*b2; acc[3][3] += a3*b3;
            }
            __syncthreads();
        }
    }
#pragma unroll
    for (int i = 0; i < 4; ++i) {
        int p = p0 + 4*tm + i;
        float4 o;
        float* op = &o.x;
#pragma unroll
        for (int j = 0; j < 4; ++j) {
            float v = acc[i][j] + bias[oc0 + 4*tn + j];
            op[j] = v > 0.f ? v : 0.f;
        }
        *(float4*)(xout + (size_t)p*512 + oc0 + 4*tn) = o;
    }
}

__global__ __launch_bounds__(256) void wprep_kernel(
    const float* __restrict__ regw, const float* __restrict__ clsw,
    const float* __restrict__ lmw, float* __restrict__ wT)
{
    int i = blockIdx.x*256 + threadIdx.x;
    if (i >= 99*512) return;
    int u = i >> 9, c = i & 511;
    float v;
    if (u < 36)      v = regw[c*72 + (u>>2)*8 + (u&3)];
    else if (u < 45) v = clsw[c*9 + (u-36)];
    else             v = lmw[c*54 + (u-45)];
    wT[i] = v;
}

__global__ __launch_bounds__(256) void heads_kernel(
    const float* __restrict__ x, const float* __restrict__ wT,
    const float* __restrict__ regb, const float* __restrict__ clsb,
    const float* __restrict__ lmb,
    float* __restrict__ lm_out, float* __restrict__ deltas,
    float* __restrict__ s_arr)
{
    __shared__ float xs[16*516];
    const int p0 = blockIdx.x * 16;
    const float4* src = (const float4*)(x + (size_t)p0*512);
    for (int i = threadIdx.x; i < 16*128; i += 256) {
        int row = i >> 7, c4 = i & 127;
        *(float4*)(xs + row*516 + c4*4) = src[row*128 + c4];
    }
    __syncthreads();
    for (int oi = threadIdx.x; oi < 99*16; oi += 256) {
        int ps = oi & 15, u = oi >> 4;
        const float4* wv = (const float4*)(wT + (u << 9));
        const float4* xv = (const float4*)(xs + ps*516);
        float acc = 0.f;
#pragma unroll 4
        for (int c = 0; c < 128; ++c) {
            float4 a = xv[c], b = wv[c];
            acc += a.x*b.x + a.y*b.y + a.z*b.z + a.w*b.w;
        }
        int p = p0 + ps;
        if (u < 36) {
            int aidx = u >> 2, r = u & 3;
            deltas[(size_t)(p*9 + aidx)*4 + r] = acc + regb[aidx*8 + r];
        } else if (u < 45) {
            float z = acc + clsb[u-36];
            s_arr[p*9 + (u-36)] = 1.f/(1.f + expf(-z));
        } else {
            lm_out[(size_t)p*54 + (u-45)] = acc + lmb[u-45];
        }
    }
}

__global__ __launch_bounds__(256) void decode_kernel(
    const float* __restrict__ deltas, float* __restrict__ s_arr,
    float* __restrict__ boxes, float* __restrict__ anch_out,
    u64* __restrict__ slot)
{
    int n = blockIdx.x*256 + threadIdx.x;
    if (n < 8) slot[n] = 0ull;
    if (n >= NANCH) return;
    int p = n / 9, a = n - 9*p;
    int y = p / FW, x = p - FW*y;
    float cx = (x + 0.5f)*STRIDE, cy = (y + 0.5f)*STRIDE;
    const float rr[3] = {0.5f, 1.f, 2.f};
    const float ss[3] = {8.f, 16.f, 32.f};
    float r = rr[a/3], sv = ss[a - (a/3)*3];
    float h  = sqrtf(sv*sv/r)*STRIDE;
    float wv = h * r;
    float x1a = cx - wv*0.5f, y1a = cy - h*0.5f;
    float x2a = cx + wv*0.5f, y2a = cy + h*0.5f;
    float4 av = {x1a, y1a, x2a, y2a};
    *(float4*)(anch_out + (size_t)4*n) = av;
    bool valid = (x1a >= 0.f) && (y1a >= 0.f) && (x2a <= IMG) && (y2a <= IMG);

    float4 d = *(const float4*)(deltas + (size_t)4*n);
    float px = cx + wv*d.x, py = cy + h*d.y;
    float pw = wv*expf(d.z), ph = h*expf(d.w);
    float bx1 = px - pw*0.5f, by1 = py - ph*0.5f;
    float4 b;
    b.x = fminf(fmaxf(bx1, 0.f), IMG);
    b.y = fminf(fmaxf(by1, 0.f), IMG);
    b.z = fminf(fmaxf(bx1 + pw, 0.f), IMG);
    b.w = fminf(fmaxf(by1 + ph, 0.f), IMG);
    *(float4*)(boxes + (size_t)4*n) = b;
    if (!valid) s_arr[n] = -1.f;
}

__global__ __launch_bounds__(256) void nms_iter_kernel(
    const float* __restrict__ boxes, float* __restrict__ s_arr,
    u64* __restrict__ slot, int k)
{
    __shared__ u64 red[4];
    int n = blockIdx.x*256 + threadIdx.x;
    float s = s_arr[n];
    if (k > 0) {
        unsigned int wn = ~(unsigned int)(slot[k-1] & 0xFFFFFFFFull);
        float4 wb = *(const float4*)(boxes + (size_t)4*wn);
        float4 b  = *(const float4*)(boxes + (size_t)4*n);
        float ix = fminf(wb.z, b.z) - fmaxf(wb.x, b.x);
        float iy = fminf(wb.w, b.w) - fmaxf(wb.y, b.y);
        float inter = fmaxf(ix, 0.f)*fmaxf(iy, 0.f);
        float a1 = (wb.z-wb.x)*(wb.w-wb.y);
        float a2 = (b.z-b.x)*(b.w-b.y);
        float iou = inter/(a1 + a2 - inter + 1e-9f);
        if (iou > 0.5f) { s = -1.f; s_arr[n] = -1.f; }
    }
    u64 packed = pack_key(s, n);
    packed = wave_max64(packed);
    if ((threadIdx.x & 63) == 0) red[threadIdx.x >> 6] = packed;
    __syncthreads();
    if (threadIdx.x == 0) {
        u64 m = red[0];
        m = m > red[1] ? m : red[1];
        m = m > red[2] ? m : red[2];
        m = m > red[3] ? m : red[3];
        atomicMax(&slot[k], m);
    }
}

__global__ void nms_fin_kernel(
    const float* __restrict__ boxes,
    const u64* __restrict__ slot, float* __restrict__ rois)
{
    int t = threadIdx.x;
    if (t < 6) {
        unsigned int n = ~(unsigned int)(slot[t] & 0xFFFFFFFFull);
        float4 b = *(const float4*)(boxes + (size_t)4*n);
        *(float4*)(rois + 4*t) = b;
    }
}

// ---------------------------------------------------------------------------
extern "C" void kernel_launch(void* const* d_in, const int* in_sizes, int n_in,
                              void* d_out, int out_size, void* d_ws, size_t ws_size,
                              hipStream_t stream)
{
    const float* f    = (const float*)d_in[0];
    const float* c1w  = (const float*)d_in[2];
    const float* c1b  = (const float*)d_in[3];
    const float* regw = (const float*)d_in[4];
    const float* regb = (const float*)d_in[5];
    const float* clsw = (const float*)d_in[6];
    const float* clsb = (const float*)d_in[7];
    const float* lmw  = (const float*)d_in[8];
    const float* lmb  = (const float*)d_in[9];

    float* out      = (float*)d_out;
    float* rois     = out;
    float* lm_out   = out + 24;
    float* anch_out = out + 24 + (size_t)NPOS*54;

    char* ws = (char*)d_ws;

    if (ws_size >= 62547968ull) {
        u64* blockmax = (u64*)ws;                                 //      1,600
        unsigned short* wh  = (unsigned short*)(ws + 2048);       //    131,072
        unsigned short* fph = (unsigned short*)(ws + 133120);     // 26,873,856
        unsigned short* wt  = (unsigned short*)(ws + 27006976);   //  4,718,592
        unsigned short* xh  = (unsigned short*)(ws + 31725568);   // 26,214,400
        float* boxes  = (float*)(ws + 57939968);                  //  3,686,400
        float* s_arr  = (float*)(ws + 61626368);                  //    921,600

        prep_kernel<<<15682, 256, 0, stream>>>(f, c1w, regw, clsw, lmw,
                                               fph, wt, wh);
        conv1_mfma_kernel<<<800, 256, 0, stream>>>(fph, wt, c1b, xh);
        heads_mfma_kernel<<<200, 256, 0, stream>>>(xh, wh, regb, clsb, lmb,
                                                   lm_out, boxes, anch_out,
                                                   s_arr, blockmax);
        for (int k = 1; k <= 5; ++k)
            nms_supp_kernel<<<200, 256, 0, stream>>>(boxes, s_arr, blockmax,
                                                     rois, k);
        nms_fin2_kernel<<<1, 256, 0, stream>>>(boxes, blockmax, rois);
    } else {
        u64* slot = (u64*)ws;
        float* wT     = (float*)(ws + 256);
        float* boxes  = (float*)(ws + 256 + 202752);
        float* deltas = (float*)(ws + 256 + 202752 + 3686400);
        float* s_arr  = (float*)(ws + 256 + 202752 + 2*3686400);
        float* x      = (float*)(ws + 256 + 202752 + 2*3686400 + 921600);

        wprep_kernel<<<(99*512 + 255)/256, 256, 0, stream>>>(regw, clsw, lmw, wT);
        conv1_kernel<<<dim3(8, 400), 256, 0, stream>>>(f, c1w, c1b, x);
        heads_kernel<<<NPOS/16, 256, 0, stream>>>(x, wT, regb, clsb, lmb,
                                                  lm_out, deltas, s_arr);
        decode_kernel<<<NANCH/256, 256, 0, stream>>>(deltas, s_arr, boxes,
                                                     anch_out, slot);
        for (int k = 0; k < 6; ++k)
            nms_iter_kernel<<<NANCH/256, 256, 0, stream>>>(boxes, s_arr, slot, k);
        nms_fin_kernel<<<1, 64, 0, stream>>>(boxes, slot, rois);
    }
}